// Round 5
// baseline (270.904 us; speedup 1.0000x reference)
//
#include <hip/hip_runtime.h>
#include <hip/hip_bf16.h>

#define N_NODES 100000
#define N_EDGES 1600000
#define D 128
#define NBLK 391          // ceil(100000/256)
#define NBUCK 782         // ceil(100000/128)

typedef short  s8v  __attribute__((ext_vector_type(8)));
typedef float  f4v  __attribute__((ext_vector_type(4)));

__device__ __forceinline__ ushort f2bf(float f) {
    uint u = __float_as_uint(f);
    return (ushort)((u + 0x7FFFu + ((u >> 16) & 1u)) >> 16);
}
__device__ __forceinline__ float bflo(uint u) { return __uint_as_float(u << 16); }
__device__ __forceinline__ float bfhi(uint u) { return __uint_as_float(u & 0xFFFF0000u); }

// ---------------------------------------------------------------------------
// wt[n][k] = bf16(w[k][n])
// ---------------------------------------------------------------------------
__global__ __launch_bounds__(256) void k_wt(const float* __restrict__ w,
                                            ushort* __restrict__ wt) {
    int i = blockIdx.x * 256 + threadIdx.x;
    if (i < D * D) {
        int k = i >> 7, n = i & 127;
        wt[n * D + k] = f2bf(w[i]);
    }
}

// ---------------------------------------------------------------------------
// supb = bf16( X @ W )  via MFMA 16x16x32 bf16
// ---------------------------------------------------------------------------
__global__ __launch_bounds__(256, 2) void k_gemm(const float* __restrict__ x,
                                                 const ushort* __restrict__ wt,
                                                 ushort* __restrict__ supb) {
    __shared__ int4 Bl4[2048];            // 32 KB
    char* Bl = (char*)Bl4;

    const int t    = threadIdx.x;
    const int lane = t & 63;
    const int w    = t >> 6;
    const int row0 = blockIdx.x * 128;

    const int4* g = (const int4*)wt;
    #pragma unroll
    for (int i = 0; i < 8; ++i) {
        int idx = t + i * 256;
        int n = idx >> 4, c = idx & 15;
        *(int4*)(Bl + ((n * 256 + c * 16) ^ ((n & 7) << 4))) = g[idx];
    }
    __syncthreads();

    f4v acc[2][8] = {};
    const int arow = row0 + w * 32 + (lane & 15);
    const int kb   = (lane >> 4) * 8;

    #pragma unroll
    for (int ks = 0; ks < 4; ++ks) {
        s8v a[2];
        #pragma unroll
        for (int m = 0; m < 2; ++m) {
            int r = arow + m * 16;
            float4 f0 = make_float4(0.f, 0.f, 0.f, 0.f);
            float4 f1 = make_float4(0.f, 0.f, 0.f, 0.f);
            if (r < N_NODES) {
                const float4* p = (const float4*)(x + (size_t)r * D + ks * 32 + kb);
                f0 = p[0];
                f1 = p[1];
            }
            s8v av;
            av[0] = (short)f2bf(f0.x); av[1] = (short)f2bf(f0.y);
            av[2] = (short)f2bf(f0.z); av[3] = (short)f2bf(f0.w);
            av[4] = (short)f2bf(f1.x); av[5] = (short)f2bf(f1.y);
            av[6] = (short)f2bf(f1.z); av[7] = (short)f2bf(f1.w);
            a[m] = av;
        }
        #pragma unroll
        for (int n = 0; n < 8; ++n) {
            int brow = n * 16 + (lane & 15);
            s8v b = *(s8v*)(Bl + ((brow * 256 + (ks * 32 + kb) * 2) ^ ((brow & 7) << 4)));
            acc[0][n] = __builtin_amdgcn_mfma_f32_16x16x32_bf16(a[0], b, acc[0][n], 0, 0, 0);
            acc[1][n] = __builtin_amdgcn_mfma_f32_16x16x32_bf16(a[1], b, acc[1][n], 0, 0, 0);
        }
    }

    __syncthreads();
    char* E = Bl + w * 8192;
    #pragma unroll
    for (int m = 0; m < 2; ++m)
        #pragma unroll
        for (int n = 0; n < 8; ++n)
            #pragma unroll
            for (int r = 0; r < 4; ++r) {
                int rl  = m * 16 + ((lane >> 4) << 2) + r;
                int col = n * 16 + (lane & 15);
                *(ushort*)(E + ((rl * 256 + col * 2) ^ ((rl & 7) << 4))) =
                    f2bf(acc[m][n][r]);
            }
    __syncthreads();
    #pragma unroll
    for (int i = 0; i < 8; ++i) {
        int idx = lane + i * 64;
        int rl = idx >> 4, c = idx & 15;
        int4 v = *(int4*)(E + ((rl * 256 + c * 16) ^ ((rl & 7) << 4)));
        int grow = row0 + w * 32 + rl;
        if (grow < N_NODES)
            *(int4*)((char*)supb + (size_t)grow * 256 + c * 16) = v;
    }
}

// ---------------------------------------------------------------------------
// CSR row_start build (zero -> hist -> 3-stage scan)
// ---------------------------------------------------------------------------
__global__ __launch_bounds__(256) void k_zero(int* __restrict__ counts,
                                              int* __restrict__ bcur) {
    int i = blockIdx.x * 256 + threadIdx.x;
    if (i < N_NODES) counts[i] = 0;
    if (i < NBUCK * 16) bcur[i] = 0;
}

__global__ __launch_bounds__(256) void k_hist(const int* __restrict__ er,
                                              int* __restrict__ counts) {
    int e = blockIdx.x * 256 + threadIdx.x;
    if (e < N_EDGES) atomicAdd(&counts[er[e]], 1);
}

__global__ __launch_bounds__(256) void k_scan1(const int* __restrict__ counts,
                                               int* __restrict__ incl,
                                               int* __restrict__ partials) {
    __shared__ int s[256];
    int i = blockIdx.x * 256 + threadIdx.x;
    s[threadIdx.x] = (i < N_NODES) ? counts[i] : 0;
    __syncthreads();
    for (int off = 1; off < 256; off <<= 1) {
        int t = (threadIdx.x >= off) ? s[threadIdx.x - off] : 0;
        __syncthreads();
        s[threadIdx.x] += t;
        __syncthreads();
    }
    if (i < N_NODES) incl[i] = s[threadIdx.x];
    if (threadIdx.x == 255) partials[blockIdx.x] = s[255];
}

__global__ __launch_bounds__(512) void k_scan2(int* __restrict__ partials,
                                               int* __restrict__ row_start) {
    __shared__ int s[512];
    int j = threadIdx.x;
    s[j] = (j < NBLK) ? partials[j] : 0;
    __syncthreads();
    for (int off = 1; off < 512; off <<= 1) {
        int t = (j >= off) ? s[j - off] : 0;
        __syncthreads();
        s[j] += t;
        __syncthreads();
    }
    if (j < NBLK) partials[j] = s[j];
    if (j == NBLK - 1) row_start[N_NODES] = s[j];
}

__global__ __launch_bounds__(256) void k_scan3(int* __restrict__ rs,
                                               const int* __restrict__ counts,
                                               const int* __restrict__ partials) {
    int i = blockIdx.x * 256 + threadIdx.x;
    if (i >= N_NODES) return;
    int base = (blockIdx.x > 0) ? partials[blockIdx.x - 1] : 0;
    rs[i] = base + rs[i] - counts[i];
}

// ---------------------------------------------------------------------------
// Phase A: coarse partition into 128-row buckets (dense contiguous windows
// -> dirty lines merge in L2). meta = (local_row<<17) | col
// ---------------------------------------------------------------------------
__global__ __launch_bounds__(256) void k_part(const int* __restrict__ er,
                                              const int* __restrict__ ec,
                                              const float* __restrict__ ev,
                                              const int* __restrict__ row_start,
                                              int* __restrict__ bcur,
                                              int2* __restrict__ tmp) {
    int e = blockIdx.x * 256 + threadIdx.x;
    if (e >= N_EDGES) return;
    int r = er[e];
    int b = r >> 7;
    int p = row_start[b << 7] + atomicAdd(&bcur[b << 4], 1);
    tmp[p] = make_int2(((r & 127) << 17) | ec[e], __float_as_int(ev[e]));
}

// ---------------------------------------------------------------------------
// Phase B: exact CSR placement within each bucket; per-row cursors in LDS.
// ---------------------------------------------------------------------------
__global__ __launch_bounds__(256) void k_sort(const int2* __restrict__ tmp,
                                              const int* __restrict__ row_start,
                                              int2* __restrict__ scv) {
    __shared__ int cur[128];
    __shared__ int rs[129];
    const int tx = (int)threadIdx.x;
    const int b = blockIdx.x;
    const int r0 = b << 7;
    const int nrows = (N_NODES - r0 < 128) ? (N_NODES - r0) : 128;

    if (tx < 128) cur[tx] = 0;
    if (tx <= nrows) {
        int idx = r0 + tx;
        if (idx > N_NODES) idx = N_NODES;
        rs[tx] = row_start[idx];
    }
    __syncthreads();

    const int base = rs[0];
    const int count = rs[nrows] - base;

    for (int i = tx; i < count; i += 256) {
        int2 t = tmp[base + i];
        int lr = t.x >> 17;
        int c  = t.x & 0x1FFFF;
        int p  = rs[lr] + atomicAdd(&cur[lr], 1);
        scv[p] = make_int2(c, t.y);
    }
}

// ---------------------------------------------------------------------------
// CSR SpMM: one wave per row; half-wave per edge; uint2 (4 bf16) per lane;
// __shfl_xor(32) fold; float4 store with bias.
// ---------------------------------------------------------------------------
__global__ __launch_bounds__(256) void k_spmm(const ushort* __restrict__ supb,
                                              const int* __restrict__ row_start,
                                              const int2* __restrict__ scv,
                                              const float* __restrict__ bias,
                                              float* __restrict__ out) {
    const int row = blockIdx.x * 4 + (threadIdx.x >> 6);
    if (row >= N_NODES) return;
    const int lane = threadIdx.x & 63;
    const int sub  = lane >> 5;
    const int sl   = lane & 31;

    const int j0  = row_start[row];
    const int end = row_start[row + 1];
    const uint2* S = (const uint2*)supb;

    float4 acc = make_float4(0.f, 0.f, 0.f, 0.f);

    int j = j0;
    for (; j + 3 < end; j += 4) {
        int2 e0 = scv[j + sub];
        int2 e1 = scv[j + 2 + sub];
        uint2 s0 = S[(size_t)e0.x * 32 + sl];
        uint2 s1 = S[(size_t)e1.x * 32 + sl];
        float v0 = __int_as_float(e0.y), v1 = __int_as_float(e1.y);
        acc.x += v0 * bflo(s0.x) + v1 * bflo(s1.x);
        acc.y += v0 * bfhi(s0.x) + v1 * bfhi(s1.x);
        acc.z += v0 * bflo(s0.y) + v1 * bflo(s1.y);
        acc.w += v0 * bfhi(s0.y) + v1 * bfhi(s1.y);
    }
    for (; j < end; j += 2) {
        int jj = j + sub;
        if (jj > end - 1) jj = end - 1;
        int2 e = scv[jj];
        float v = (j + sub < end) ? __int_as_float(e.y) : 0.f;
        uint2 s = S[(size_t)e.x * 32 + sl];
        acc.x += v * bflo(s.x);
        acc.y += v * bfhi(s.x);
        acc.z += v * bflo(s.y);
        acc.w += v * bfhi(s.y);
    }

    acc.x += __shfl_xor(acc.x, 32);
    acc.y += __shfl_xor(acc.y, 32);
    acc.z += __shfl_xor(acc.z, 32);
    acc.w += __shfl_xor(acc.w, 32);

    if (sub == 0) {
        float4 bb = *(const float4*)(bias + 4 * sl);
        acc.x += bb.x; acc.y += bb.y; acc.z += bb.z; acc.w += bb.w;
        *(float4*)(out + (size_t)row * D + 4 * sl) = acc;
    }
}

extern "C" void kernel_launch(void* const* d_in, const int* in_sizes, int n_in,
                              void* d_out, int out_size, void* d_ws, size_t ws_size,
                              hipStream_t stream) {
    const float* x    = (const float*)d_in[0];
    const float* w    = (const float*)d_in[1];
    const float* bias = (const float*)d_in[2];
    const float* ev   = (const float*)d_in[3];
    const int*   er   = (const int*)d_in[4];
    const int*   ec   = (const int*)d_in[5];
    float* out = (float*)d_out;

    // workspace layout (16B aligned), ~52.1 MB
    char* ws = (char*)d_ws;
    ushort* supb      = (ushort*)(ws);                  // 25,600,000
    int*    row_start = (int*)   (ws + 25600000);       //    400,016
    int*    counts    = (int*)   (ws + 26000016);       //    400,000
    int*    partials  = (int*)   (ws + 26400016);       //      1,616
    int*    bcur      = (int*)   (ws + 26401632);       //     50,048
    int2*   tmp       = (int2*)  (ws + 26451680);       // 12,800,000
    int2*   scv       = (int2*)  (ws + 39251680);       // 12,800,000
    ushort* wt        = (ushort*)(ws + 52051680);       //     32,768

    k_wt  <<<64, 256, 0, stream>>>(w, wt);
    k_gemm<<<(N_NODES + 127) / 128, 256, 0, stream>>>(x, wt, supb);

    k_zero <<<NBLK, 256, 0, stream>>>(counts, bcur);
    k_hist <<<(N_EDGES + 255) / 256, 256, 0, stream>>>(er, counts);
    k_scan1<<<NBLK, 256, 0, stream>>>(counts, row_start, partials);
    k_scan2<<<1, 512, 0, stream>>>(partials, row_start);
    k_scan3<<<NBLK, 256, 0, stream>>>(row_start, counts, partials);

    k_part <<<(N_EDGES + 255) / 256, 256, 0, stream>>>(er, ec, ev, row_start,
                                                       bcur, tmp);
    k_sort <<<NBUCK, 256, 0, stream>>>(tmp, row_start, scv);

    k_spmm<<<N_NODES / 4, 256, 0, stream>>>(supb, row_start, scv, bias, out);
}